// Round 7
// baseline (634.551 us; speedup 1.0000x reference)
//
#include <hip/hip_runtime.h>
#include <hip/hip_bf16.h>

typedef __attribute__((ext_vector_type(8)))  short bf16x8;
typedef __attribute__((ext_vector_type(16))) float f32x16;

#define KC1 15            // layer-1 k-chunks of 16 (224 feats + 16 bias-pad)
#define KC2 17            // layer-2 k-chunks of 16 (256 hidden + 16 bias-pad)
#define NT1 8             // layer-1 n-tiles of 32 (256 hidden)
#define W1L_EL (NT1 * KC1 * 512)   // 61440 bf16
#define W2L_EL (2 * KC2 * 512)     // 17408 bf16
#define NODES_EL 3200000           // 50000*64
#define GLOB_EL 256                // 8*32
#define LDS_SHORTS (W1L_EL + W2L_EL)   // 78848 shorts = 157,696 B
#define NTILES 25000               // 800000 / 32
#define NWAVES 2048                // 256 blocks * 8 waves

static __device__ __forceinline__ short f2bf(float x) {
  union { __hip_bfloat16 h; short s; } u; u.h = __float2bfloat16(x); return u.s;
}
static __device__ __forceinline__ int cvtpk(float lo, float hi) {
  int d;
  asm("v_cvt_pk_bf16_f32 %0, %1, %2" : "=v"(d) : "v"(lo), "v"(hi));
  return d;
}
// v_permlane32_swap_b32 vdst, vsrc (HK-validated convention):
//   new_dst = (lane<32) ? old_dst : partner(old_src)
//   new_src = (lane<32) ? partner(old_dst) : old_src
static __device__ __forceinline__ void plswap(int& dst, int& src) {
  asm("v_permlane32_swap_b32 %0, %1" : "+v"(dst), "+v"(src));
}
static __device__ __forceinline__ bf16x8 pk8(float4 a, float4 b) {
  bf16x8 r;
  r[0] = f2bf(a.x); r[1] = f2bf(a.y); r[2] = f2bf(a.z); r[3] = f2bf(a.w);
  r[4] = f2bf(b.x); r[5] = f2bf(b.y); r[6] = f2bf(b.z); r[7] = f2bf(b.w);
  return r;
}

typedef __attribute__((address_space(3))) unsigned as3_u32;
typedef __attribute__((address_space(1))) unsigned as1_u32;
static __device__ __forceinline__ void gload16(const void* g, void* l) {
  __builtin_amdgcn_global_load_lds((const as1_u32*)g, (as3_u32*)l, 16, 0, 0);
}

// ---- prepass: fragment-ordered bf16 weights (+bias rows) and bf16 tables ----
// W1L frag f = nt*KC1+kc, lane l, elem j:  W1ext[n=nt*32+(l&31)][k=kc*16+(l>>5)*8+j]
// W2L frag f = jt*KC2+kc:                  W2ext[oc=jt*32+(l&31)][k=...]
__global__ void prep(const float* __restrict__ nodes, const float* __restrict__ glob,
                     const float* __restrict__ W1, const float* __restrict__ b1,
                     const float* __restrict__ W2, const float* __restrict__ b2,
                     short* __restrict__ wsW, short* __restrict__ nodesBF,
                     short* __restrict__ globBF) {
  int i = blockIdx.x * 256 + threadIdx.x;
  if (i < W1L_EL) {
    int j = i & 7, l = (i >> 3) & 63, f = i >> 9;
    int kc = f % KC1, nt = f / KC1;
    int n = nt * 32 + (l & 31);
    int k = kc * 16 + (l >> 5) * 8 + j;
    float v = (k < 224) ? W1[k * 256 + n] : (k == 224 ? b1[n] : 0.f);
    wsW[i] = f2bf(v);
    return;
  }
  i -= W1L_EL;
  if (i < W2L_EL) {
    int j = i & 7, l = (i >> 3) & 63, f = i >> 9;
    int kc = f % KC2, jt = f / KC2;
    int oc = jt * 32 + (l & 31);
    int k = kc * 16 + (l >> 5) * 8 + j;
    float v = (k < 256) ? W2[k * 64 + oc] : (k == 256 ? b2[oc] : 0.f);
    wsW[W1L_EL + i] = f2bf(v);
    return;
  }
  i -= W2L_EL;
  if (i < NODES_EL) { nodesBF[i] = f2bf(nodes[i]); return; }
  i -= NODES_EL;
  if (i < GLOB_EL) globBF[i] = f2bf(glob[i]);
}

// ---- main: barrier-free per-wave streams; gather -> MFMA-direct ----
__global__ __launch_bounds__(512, 2) void edge_mlp(
    const float* __restrict__ edges,
    const int* __restrict__ recv,
    const int* __restrict__ send,
    const int* __restrict__ egi,
    const short* __restrict__ nodesBF,
    const short* __restrict__ globBF,
    const short* __restrict__ wsW,
    float* __restrict__ out)
{
  __shared__ short WL[LDS_SHORTS];   // 157,696 B -> 1 block/CU

  // stage fragment-ordered weights linearly (16B per lane-slot)
  {
    const int t = threadIdx.x;
    #pragma unroll
    for (int it = 0; it < 19; ++it) {
      int slot = it * 512 + t;
      gload16(wsW + slot * 8, (char*)WL + slot * 16);
    }
    int slot = 19 * 512 + t;                 // 9856 slots total
    if (slot < LDS_SHORTS / 8) gload16(wsW + slot * 8, (char*)WL + slot * 16);
  }
  __syncthreads();   // only barrier in the kernel (drains vmcnt too)

  const int lane = threadIdx.x & 63;
  const int r32  = lane & 31;     // persistent m-row identity
  const int h    = lane >> 5;     // half-wave
  const int wave_gid = blockIdx.x * 8 + (threadIdx.x >> 6);

  const bf16x8* __restrict__ WF = reinterpret_cast<const bf16x8*>(WL);

  // constant bias-column B-frag: k_local==0 -> 1.0 (h==0, j==0), else 0
  bf16x8 bC;
  {
    union { int4 i; bf16x8 v; } u;
    u.i.x = (h == 0) ? 0x3F80 : 0; u.i.y = 0; u.i.z = 0; u.i.w = 0;
    bC = u.v;
  }

  for (int tile = wave_gid; tile < NTILES; tile += NWAVES) {
    const int m = tile * 32 + r32;

    // ---- indices + direct-to-register fragment gathers (all independent) ----
    const int ir = recv[m];
    const int is = send[m];
    const int ig = egi[m];

    const float* ep = edges + (size_t)m * 64 + h * 8;
    float4 ef[8];
    #pragma unroll
    for (int c = 0; c < 4; ++c) {
      ef[2 * c]     = *reinterpret_cast<const float4*>(ep + c * 16);
      ef[2 * c + 1] = *reinterpret_cast<const float4*>(ep + c * 16 + 4);
    }
    const short* rp = nodesBF + (size_t)ir * 64 + h * 8;
    const short* sp = nodesBF + (size_t)is * 64 + h * 8;
    const short* gp = globBF + (size_t)ig * 32 + h * 8;
    bf16x8 bR[4], bS[4], bG[2];
    #pragma unroll
    for (int c = 0; c < 4; ++c) bR[c] = *reinterpret_cast<const bf16x8*>(rp + c * 16);
    #pragma unroll
    for (int c = 0; c < 4; ++c) bS[c] = *reinterpret_cast<const bf16x8*>(sp + c * 16);
    #pragma unroll
    for (int c = 0; c < 2; ++c) bG[c] = *reinterpret_cast<const bf16x8*>(gp + c * 16);
    bf16x8 bE[4];
    #pragma unroll
    for (int c = 0; c < 4; ++c) bE[c] = pk8(ef[2 * c], ef[2 * c + 1]);

    // ---- layer 1: acc[nt] = sum_kc W1frag(nt,kc) x Bfrag(kc);  D[n][m] ----
    f32x16 acc[8];
    #pragma unroll
    for (int nt = 0; nt < 8; ++nt)
      #pragma unroll
      for (int q = 0; q < 16; ++q) acc[nt][q] = 0.f;

    __builtin_amdgcn_s_setprio(1);
    #pragma unroll
    for (int kc = 0; kc < KC1; ++kc) {
      bf16x8 B = (kc < 4) ? bE[kc]
               : (kc < 8) ? bR[kc - 4]
               : (kc < 12) ? bS[kc - 8]
               : (kc < 14) ? bG[kc - 12] : bC;
      #pragma unroll
      for (int nt = 0; nt < 8; ++nt)
        acc[nt] = __builtin_amdgcn_mfma_f32_32x32x16_bf16(
            WF[(nt * KC1 + kc) * 64 + lane], B, acc[nt], 0, 0, 0);
    }
    __builtin_amdgcn_s_setprio(0);

    // ---- ReLU in-register (bias already accumulated via MFMA) ----
    #pragma unroll
    for (int nt = 0; nt < 8; ++nt)
      #pragma unroll
      for (int q = 0; q < 16; ++q)
        acc[nt][q] = fmaxf(acc[nt][q], 0.f);

    // ---- layer 2: H-frags assembled in-register (cvt_pk + permlane32_swap) ----
    f32x16 acc2[2];
    #pragma unroll
    for (int jt = 0; jt < 2; ++jt)
      #pragma unroll
      for (int q = 0; q < 16; ++q) acc2[jt][q] = 0.f;

    __builtin_amdgcn_s_setprio(1);
    #pragma unroll
    for (int kc = 0; kc < KC2; ++kc) {
      bf16x8 B2;
      if (kc == 16) {
        B2 = bC;
      } else {
        const int nt = kc >> 1, r0 = (kc & 1) * 8;
        int a0  = cvtpk(acc[nt][r0 + 0], acc[nt][r0 + 1]);
        int a1  = cvtpk(acc[nt][r0 + 2], acc[nt][r0 + 3]);
        int b0  = cvtpk(acc[nt][r0 + 4], acc[nt][r0 + 5]);
        int b1d = cvtpk(acc[nt][r0 + 6], acc[nt][r0 + 7]);
        // HK convention: after swap, h=0 frag = rows[0..7], h=1 frag = rows[8..15]
        plswap(a0, b0);    // a0' = h? partner(b0) : own(a0);  b0' = h? own(b0) : partner(a0)
        plswap(a1, b1d);
        union { int4 i; bf16x8 v; } u;
        u.i.x = a0; u.i.y = a1; u.i.z = b0; u.i.w = b1d;
        B2 = u.v;
      }
      #pragma unroll
      for (int jt = 0; jt < 2; ++jt)
        acc2[jt] = __builtin_amdgcn_mfma_f32_32x32x16_bf16(
            WF[(NT1 * KC1 + jt * KC2 + kc) * 64 + lane], B2, acc2[jt], 0, 0, 0);
    }
    __builtin_amdgcn_s_setprio(0);

    // ---- store: lane owns row m; oc = jt*32 + q*8 + h*4 + 0..3 ----
    float* orow = out + (size_t)m * 64 + h * 4;
    #pragma unroll
    for (int jt = 0; jt < 2; ++jt)
      #pragma unroll
      for (int q = 0; q < 4; ++q) {
        float4 o;
        o.x = acc2[jt][4 * q + 0];
        o.y = acc2[jt][4 * q + 1];
        o.z = acc2[jt][4 * q + 2];
        o.w = acc2[jt][4 * q + 3];
        *reinterpret_cast<float4*>(orow + jt * 32 + q * 8) = o;
      }
  }
}

extern "C" void kernel_launch(void* const* d_in, const int* in_sizes, int n_in,
                              void* d_out, int out_size, void* d_ws, size_t ws_size,
                              hipStream_t stream) {
  (void)in_sizes; (void)n_in; (void)out_size; (void)ws_size;
  const float* edges = (const float*)d_in[0];
  const float* nodes = (const float*)d_in[1];
  const float* glob  = (const float*)d_in[2];
  const int*   recv  = (const int*)d_in[3];
  const int*   send  = (const int*)d_in[4];
  const int*   egi   = (const int*)d_in[5];
  const float* W1    = (const float*)d_in[6];
  const float* b1    = (const float*)d_in[7];
  const float* W2    = (const float*)d_in[8];
  const float* b2    = (const float*)d_in[9];
  float* out = (float*)d_out;

  short* wsW     = (short*)d_ws;                 // W1L ++ W2L (78,848 shorts)
  short* nodesBF = wsW + LDS_SHORTS;             // 3,200,000
  short* globBF  = nodesBF + NODES_EL;           // 256

  const int prep_total = W1L_EL + W2L_EL + NODES_EL + GLOB_EL;  // 3,279,104
  prep<<<prep_total / 256, 256, 0, stream>>>(nodes, glob, W1, b1, W2, b2,
                                             wsW, nodesBF, globBF);
  edge_mlp<<<256, 512, 0, stream>>>(edges, recv, send, egi,
                                    nodesBF, globBF, wsW, out);
}

// Round 9
// 294.156 us; speedup vs baseline: 2.1572x; 2.1572x over previous
//
#include <hip/hip_runtime.h>
#include <hip/hip_bf16.h>

typedef __attribute__((ext_vector_type(8)))  short bf16x8;
typedef __attribute__((ext_vector_type(16))) float f32x16;

#define KC1 15                      // 224 feats + bias-ext = 240 = 15 k-chunks of 16
#define W1L_EL (8 * KC1 * 512)      // 61440 bf16, frag-ordered
#define W2L_EL (2 * 16 * 512)       // 16384 bf16, frag-ordered (no bias)
#define NODES_EL 3200000            // 50000*64
#define GLOB_EL 256                 // 8*32
#define NTILES 25000                // 800000 / 32
#define NBLK 2048

// LDS map (bytes): two X buffers + H exchange = 49,152 total
#define OFF_BUF0 0
#define OFF_BUF1 16384
#define OFF_HX   32768

#define MFMA32(a,b,c) __builtin_amdgcn_mfma_f32_32x32x16_bf16((a),(b),(c),0,0,0)

static __device__ __forceinline__ short f2bf(float x) {
  union { __hip_bfloat16 h; short s; } u; u.h = __float2bfloat16(x); return u.s;
}
static __device__ __forceinline__ int cvtpk(float lo, float hi) {
  int d;
  asm("v_cvt_pk_bf16_f32 %0, %1, %2" : "=v"(d) : "v"(lo), "v"(hi));
  return d;
}
static __device__ __forceinline__ void plswap(int& a, int& b) {
  asm("v_permlane32_swap_b32 %0, %1" : "+v"(a), "+v"(b));
}
static __device__ __forceinline__ bf16x8 cvt8(float4 a, float4 b) {
  union { int4 i; bf16x8 v; } u;
  u.i.x = cvtpk(a.x, a.y); u.i.y = cvtpk(a.z, a.w);
  u.i.z = cvtpk(b.x, b.y); u.i.w = cvtpk(b.z, b.w);
  return u.v;
}

typedef __attribute__((address_space(3))) unsigned as3_u32;
typedef __attribute__((address_space(1))) unsigned as1_u32;
static __device__ __forceinline__ void gload16(const void* g, void* l) {
  __builtin_amdgcn_global_load_lds((const as1_u32*)g, (as3_u32*)l, 16, 0, 0);
}

// ---- prepass: frag-ordered bf16 weights + bf16 tables (R7-validated) ----
__global__ void prep(const float* __restrict__ nodes, const float* __restrict__ glob,
                     const float* __restrict__ W1, const float* __restrict__ b1,
                     const float* __restrict__ W2,
                     short* __restrict__ wsW1, short* __restrict__ wsW2,
                     short* __restrict__ nodesBF, short* __restrict__ globBF) {
  int i = blockIdx.x * 256 + threadIdx.x;
  if (i < W1L_EL) {   // frag f = nt*KC1+kc: lane l, elem j -> W1ext[n][k]
    int j = i & 7, l = (i >> 3) & 63, f = i >> 9;
    int kc = f % KC1, nt = f / KC1;
    int n = nt * 32 + (l & 31);
    int k = kc * 16 + (l >> 5) * 8 + j;
    float v = (k < 224) ? W1[k * 256 + n] : (k == 224 ? b1[n] : 0.f);
    wsW1[i] = f2bf(v);
    return;
  }
  i -= W1L_EL;
  if (i < W2L_EL) {   // frag f = jt*16+kc
    int j = i & 7, l = (i >> 3) & 63, f = i >> 9;
    int kc = f & 15, jt2 = f >> 4;
    int oc = jt2 * 32 + (l & 31);
    int k = kc * 16 + (l >> 5) * 8 + j;
    wsW2[i] = f2bf(W2[k * 64 + oc]);
    return;
  }
  i -= W2L_EL;
  if (i < NODES_EL) { nodesBF[i] = f2bf(nodes[i]); return; }
  i -= NODES_EL;
  if (i < GLOB_EL) globBF[i] = f2bf(glob[i]);
}

// stage one 32-row tile into frag-ordered LDS slots via global_load_lds
#define STAGE(poff, e, idxv)                                               \
  do {                                                                     \
    if (w < 2) {                                                           \
      const float* _s = edges + ((e) + r32) * 64 + w * 32 + h * 8;         \
      char* _d = LDS + (poff) + (w * 4) * 1024 + lane * 16;                \
      gload16(_s + 0,  _d);                                                \
      gload16(_s + 4,  _d + 1024);                                         \
      gload16(_s + 16, _d + 2048);                                         \
      gload16(_s + 20, _d + 3072);                                         \
    } else {                                                               \
      const short* _s = nodesBF + (size_t)(unsigned)(idxv) * 64 + h * 8;   \
      char* _d = LDS + (poff) + ((w == 2) ? 8192 : 12288) + lane * 16;     \
      gload16(_s + 0,  _d);                                                \
      gload16(_s + 16, _d + 1024);                                         \
      gload16(_s + 32, _d + 2048);                                         \
      gload16(_s + 48, _d + 3072);                                         \
    }                                                                      \
  } while (0)

__global__ __launch_bounds__(256, 2) void edge_mlp(
    const float* __restrict__ edges,
    const int* __restrict__ recv,
    const int* __restrict__ send,
    const int* __restrict__ egi,
    const short* __restrict__ nodesBF,
    const short* __restrict__ globBF,
    const short* __restrict__ wsW1,
    const short* __restrict__ wsW2,
    const float* __restrict__ b2,
    float* __restrict__ out)
{
  __shared__ __align__(16) char LDS[49152];

  const int t = threadIdx.x;
  const int lane = t & 63;
  const int w = t >> 6;         // wave 0..3
  const int r32 = lane & 31;    // m-row identity
  const int h = lane >> 5;
  const int jt = w & 1;         // layer-2 out-col tile (redundant pairs 0/2, 1/3)
  const int bb = (w < 2) ? 0 : 2;

  // W1 frags (this wave's 64 hidden cols) + W2 frags (this wave's jt): registers
  bf16x8 w1f0[KC1], w1f1[KC1];
  #pragma unroll
  for (int kc = 0; kc < KC1; ++kc) {
    w1f0[kc] = *(const bf16x8*)(wsW1 + ((2 * w + 0) * KC1 + kc) * 512 + lane * 8);
    w1f1[kc] = *(const bf16x8*)(wsW1 + ((2 * w + 1) * KC1 + kc) * 512 + lane * 8);
  }
  bf16x8 w2f[16];
  #pragma unroll
  for (int kc = 0; kc < 16; ++kc)
    w2f[kc] = *(const bf16x8*)(wsW2 + (jt * 16 + kc) * 512 + lane * 8);

  const float4 b2v0 = *(const float4*)(b2 + jt * 32 + 8 * bb + 4 * h);
  const float4 b2v1 = *(const float4*)(b2 + jt * 32 + 8 * (bb + 1) + 4 * h);

  bf16x8 bC;   // bias-column B-frag: k_local==0 -> 1.0
  { union { int4 i; bf16x8 v; } u;
    u.i.x = (h == 0) ? 0x3F80 : 0; u.i.y = 0; u.i.z = 0; u.i.w = 0; bC = u.v; }

  int tile = blockIdx.x;
  long eC = (long)tile * 32;

  // ---- prologue: stage tile0, prefetch tile1 indices ----
  int idxv = 0;
  if (w == 2) idxv = recv[eC + r32];
  else if (w == 3) idxv = send[eC + r32];
  int ig = egi[eC + r32];
  asm volatile("s_waitcnt vmcnt(0)" ::: "memory");
  STAGE(OFF_BUF0, eC, idxv);
  bf16x8 gv0 = *(const bf16x8*)(globBF + (size_t)(unsigned)ig * 32 + h * 8);
  bf16x8 gv1 = *(const bf16x8*)(globBF + (size_t)(unsigned)ig * 32 + 16 + h * 8);
  {
    int tn = tile + NBLK;
    long eN = (tn < NTILES) ? (long)tn * 32 : eC;
    if (w == 2) idxv = recv[eN + r32];
    else if (w == 3) idxv = send[eN + r32];
    ig = egi[eN + r32];
  }
  asm volatile("s_waitcnt vmcnt(0)" ::: "memory");
  __builtin_amdgcn_s_barrier();

  bf16x8 ngv0, ngv1;
  int nidx = 0, nig = 0;
  int p = 0;

  #pragma unroll 1
  for (; tile < NTILES; tile += NBLK) {
    eC = (long)tile * 32;
    const int pin  = p ? OFF_BUF1 : OFF_BUF0;
    const int pout = p ? OFF_BUF0 : OFF_BUF1;

    // ---- [1] layer 1: acc[c] += W1frag x Xfrag over 15 k-chunks ----
    f32x16 acc0, acc1;
    #pragma unroll
    for (int q = 0; q < 16; ++q) { acc0[q] = 0.f; acc1[q] = 0.f; }

    #pragma unroll
    for (int kc = 0; kc < 4; ++kc) {          // edges (f32 in LDS -> cvt)
      float4 fa = *(const float4*)(LDS + pin + kc * 2048 + lane * 16);
      float4 fb = *(const float4*)(LDS + pin + kc * 2048 + 1024 + lane * 16);
      bf16x8 xa = cvt8(fa, fb);
      acc0 = MFMA32(w1f0[kc], xa, acc0);
      acc1 = MFMA32(w1f1[kc], xa, acc1);
    }
    #pragma unroll
    for (int kc = 4; kc < 8; ++kc) {          // recv rows
      bf16x8 xa = *(const bf16x8*)(LDS + pin + 8192 + (kc - 4) * 1024 + lane * 16);
      acc0 = MFMA32(w1f0[kc], xa, acc0);
      acc1 = MFMA32(w1f1[kc], xa, acc1);
    }
    #pragma unroll
    for (int kc = 8; kc < 12; ++kc) {         // send rows
      bf16x8 xa = *(const bf16x8*)(LDS + pin + 12288 + (kc - 8) * 1024 + lane * 16);
      acc0 = MFMA32(w1f0[kc], xa, acc0);
      acc1 = MFMA32(w1f1[kc], xa, acc1);
    }
    acc0 = MFMA32(w1f0[12], gv0, acc0);  acc1 = MFMA32(w1f1[12], gv0, acc1);
    acc0 = MFMA32(w1f0[13], gv1, acc0);  acc1 = MFMA32(w1f1[13], gv1, acc1);
    acc0 = MFMA32(w1f0[14], bC,  acc0);  acc1 = MFMA32(w1f1[14], bC,  acc1);

    // ---- [2] stage tile t+1 into the other buffer (overlaps [3]) ----
    {
      int tn = tile + NBLK;
      long eN = (tn < NTILES) ? (long)tn * 32 : eC;
      STAGE(pout, eN, idxv);
      ngv0 = *(const bf16x8*)(globBF + (size_t)(unsigned)ig * 32 + h * 8);
      ngv1 = *(const bf16x8*)(globBF + (size_t)(unsigned)ig * 32 + 16 + h * 8);
      int tn2 = tn + NBLK;
      long eN2 = (tn2 < NTILES) ? (long)tn2 * 32 : eN;
      nidx = 0;
      if (w == 2) nidx = recv[eN2 + r32];
      else if (w == 3) nidx = send[eN2 + r32];
      nig = egi[eN2 + r32];
    }

    // ---- [3] ReLU, in-register handoff (R7-validated), H exchange, layer 2 ----
    #pragma unroll
    for (int q = 0; q < 16; ++q) {
      acc0[q] = fmaxf(acc0[q], 0.f);
      acc1[q] = fmaxf(acc1[q], 0.f);
    }
    #pragma unroll
    for (int i = 0; i < 4; ++i) {
      f32x16 A = (i < 2) ? acc0 : acc1;
      const int r0 = (i & 1) * 8;
      int a0  = cvtpk(A[r0 + 0], A[r0 + 1]);
      int a1  = cvtpk(A[r0 + 2], A[r0 + 3]);
      int b0  = cvtpk(A[r0 + 4], A[r0 + 5]);
      int b1d = cvtpk(A[r0 + 6], A[r0 + 7]);
      plswap(a0, b0); plswap(a1, b1d);
      union { int4 iv; bf16x8 v; } u;
      u.iv.x = a0; u.iv.y = a1; u.iv.z = b0; u.iv.w = b1d;
      *(bf16x8*)(LDS + OFF_HX + (w * 4 + i) * 1024 + lane * 16) = u.v;
    }
    asm volatile("s_waitcnt lgkmcnt(0)" ::: "memory");
    __builtin_amdgcn_s_barrier();

    f32x16 acc2;
    #pragma unroll
    for (int q = 0; q < 16; ++q) acc2[q] = 0.f;
    #pragma unroll
    for (int kc = 0; kc < 16; ++kc) {
      bf16x8 hb = *(const bf16x8*)(LDS + OFF_HX + kc * 1024 + lane * 16);
      acc2 = MFMA32(w2f[kc], hb, acc2);
    }

    {
      float* orow = out + (eC + r32) * 64 + jt * 32 + 4 * h;
      float4 o0, o1;
      o0.x = acc2[4 * bb + 0] + b2v0.x;
      o0.y = acc2[4 * bb + 1] + b2v0.y;
      o0.z = acc2[4 * bb + 2] + b2v0.z;
      o0.w = acc2[4 * bb + 3] + b2v0.w;
      o1.x = acc2[4 * bb + 4] + b2v1.x;
      o1.y = acc2[4 * bb + 5] + b2v1.y;
      o1.z = acc2[4 * bb + 6] + b2v1.z;
      o1.w = acc2[4 * bb + 7] + b2v1.w;
      *(float4*)(orow + 8 * bb) = o0;
      *(float4*)(orow + 8 * bb + 8) = o1;
    }

    // ---- [4] drain staging; rotate ----
    asm volatile("s_waitcnt vmcnt(0)" ::: "memory");
    __builtin_amdgcn_s_barrier();
    gv0 = ngv0; gv1 = ngv1; idxv = nidx; ig = nig;
    p ^= 1;
  }
}

extern "C" void kernel_launch(void* const* d_in, const int* in_sizes, int n_in,
                              void* d_out, int out_size, void* d_ws, size_t ws_size,
                              hipStream_t stream) {
  (void)in_sizes; (void)n_in; (void)out_size; (void)ws_size;
  const float* edges = (const float*)d_in[0];
  const float* nodes = (const float*)d_in[1];
  const float* glob  = (const float*)d_in[2];
  const int*   recv  = (const int*)d_in[3];
  const int*   send  = (const int*)d_in[4];
  const int*   egi   = (const int*)d_in[5];
  const float* W1    = (const float*)d_in[6];
  const float* b1    = (const float*)d_in[7];
  const float* W2    = (const float*)d_in[8];
  const float* b2    = (const float*)d_in[9];
  float* out = (float*)d_out;

  short* wsW1    = (short*)d_ws;                 // 61440
  short* wsW2    = wsW1 + W1L_EL;                // 16384
  short* nodesBF = wsW2 + W2L_EL;                // 3,200,000
  short* globBF  = nodesBF + NODES_EL;           // 256

  const int prep_total = W1L_EL + W2L_EL + NODES_EL + GLOB_EL;  // 3,278,080
  prep<<<prep_total / 256, 256, 0, stream>>>(nodes, glob, W1, b1, W2,
                                             wsW1, wsW2, nodesBF, globBF);
  edge_mlp<<<NBLK, 256, 0, stream>>>(edges, recv, send, egi, nodesBF, globBF,
                                     wsW1, wsW2, b2, out);
}